// Round 4
// baseline (15.293 us; speedup 1.0000x reference)
//
#include <hip/hip_runtime.h>
#include <stdint.h>

#define NUM_GRAPHS 8192
#define NODES_PER_GRAPH 128
#define TOTAL_NODES (NUM_GRAPHS * NODES_PER_GRAPH)
#define C 128
#define GGROUPS (NUM_GRAPHS / 16)   // 512 graph-groups of 16
#define CSPLIT 4                    // each wave does 2 of the 8 col-tiles

typedef __attribute__((ext_vector_type(8))) short bf16x8;
typedef __attribute__((ext_vector_type(4))) float f32x4;

// f32 -> bf16 bits, round-to-nearest-even
static __device__ __forceinline__ short f2bf(float f) {
    union { float f; uint32_t u; } v; v.f = f;
    const uint32_t u = v.u;
    return (short)((u + 0x7fffu + ((u >> 16) & 1u)) >> 16);
}

// Fused: one wave per (16 graphs x 32 cols). grid = CSPLIT*GGROUPS blocks of 64.
// bid%GGROUPS = graph-group -> all col-splits of a group share bid%8 (same XCD).
//
// Critical-path trick: the first-node index of graph g is ALWAYS g*128 for a
// uniform sorted batch. We speculatively issue the x-row loads at that guess
// in parallel with the batch[] verification loads (no dependency), and only
// re-gather under a never-taken divergent fallback (full lower_bound, correct
// for any sorted batch). One memory latency on the chain instead of two.
__global__ __launch_bounds__(64) void pool_linear_fused(
        const float* __restrict__ x, const int* __restrict__ batch,
        const float* __restrict__ W, const float* __restrict__ bias,
        float* __restrict__ out) {
    const int bid = blockIdx.x;
    const int gg  = bid & (GGROUPS - 1);   // graph-group
    const int cth = bid >> 9;              // 0..3 -> col-tiles 2*cth, 2*cth+1

    const int l  = threadIdx.x;
    const int r  = l & 15;   // A-row / B-col / D-col within tile
    const int kg = l >> 4;   // k-group
    const int gbase = gg * 16;
    const int g  = gbase + r;

    // --- speculative gather at guessed first index ---
    const int p = g * NODES_PER_GRAPH;
    const float* xs = x + (size_t)p * C;
    float4 L[8];
#pragma unroll
    for (int j = 0; j < 8; ++j) {
        // k-layout: chunk kc covers k in [kc*32 + kg*8, +8); j = kc*2 + half
        const int k0 = (j >> 1) * 32 + kg * 8 + (j & 1) * 4;
        L[j] = *reinterpret_cast<const float4*>(xs + k0);
    }

    // --- verification (independent loads; overlaps with the gather above) ---
    const int bp  = batch[p];
    const int bpm = (p == 0) ? (g - 1) : batch[p - 1];
    if (!(bp == g && bpm < g)) {           // never taken for uniform batch
        int lo = 0, hi = TOTAL_NODES;
        while (lo < hi) {
            const int mid = (lo + hi) >> 1;
            if (batch[mid] < g) lo = mid + 1; else hi = mid;
        }
        const float* xr = x + (size_t)lo * C;
#pragma unroll
        for (int j = 0; j < 8; ++j) {
            const int k0 = (j >> 1) * 32 + kg * 8 + (j & 1) * 4;
            L[j] = *reinterpret_cast<const float4*>(xr + k0);
        }
    }

    bf16x8 a[4];
#pragma unroll
    for (int kc = 0; kc < 4; ++kc) {
        const float4 lo = L[kc * 2], hi = L[kc * 2 + 1];
        a[kc][0] = f2bf(lo.x); a[kc][1] = f2bf(lo.y); a[kc][2] = f2bf(lo.z); a[kc][3] = f2bf(lo.w);
        a[kc][4] = f2bf(hi.x); a[kc][5] = f2bf(hi.y); a[kc][6] = f2bf(hi.z); a[kc][7] = f2bf(hi.w);
    }

#pragma unroll
    for (int t = 0; t < 2; ++t) {
        const int ct  = cth * 2 + t;
        const int col = ct * 16 + r;                 // B col = D col = lane&15
        const float* wrow = W + (size_t)col * C;     // out[g][col] = sum_k x[fi][k]*W[col][k]
        const float bc = bias[col];
        f32x4 acc = {bc, bc, bc, bc};
#pragma unroll
        for (int kc = 0; kc < 4; ++kc) {
            const int k0 = kc * 32 + kg * 8;
            const float4 lo = *reinterpret_cast<const float4*>(wrow + k0);
            const float4 hi = *reinterpret_cast<const float4*>(wrow + k0 + 4);
            bf16x8 bf;
            bf[0] = f2bf(lo.x); bf[1] = f2bf(lo.y); bf[2] = f2bf(lo.z); bf[3] = f2bf(lo.w);
            bf[4] = f2bf(hi.x); bf[5] = f2bf(hi.y); bf[6] = f2bf(hi.z); bf[7] = f2bf(hi.w);
            acc = __builtin_amdgcn_mfma_f32_16x16x32_bf16(a[kc], bf, acc, 0, 0, 0);
        }
        // C/D layout: col = lane&15, row = (lane>>4)*4 + reg
#pragma unroll
        for (int reg = 0; reg < 4; ++reg) {
            const int row = gbase + kg * 4 + reg;
            out[(size_t)row * C + col] = acc[reg];
        }
    }
}

extern "C" void kernel_launch(void* const* d_in, const int* in_sizes, int n_in,
                              void* d_out, int out_size, void* d_ws, size_t ws_size,
                              hipStream_t stream) {
    const float* x     = (const float*)d_in[0];
    const int*   batch = (const int*)d_in[1];
    const float* W     = (const float*)d_in[2];
    const float* b     = (const float*)d_in[3];
    float*       out   = (float*)d_out;

    pool_linear_fused<<<CSPLIT * GGROUPS, 64, 0, stream>>>(x, batch, W, b, out);
}

// Round 5
// 13.195 us; speedup vs baseline: 1.1590x; 1.1590x over previous
//
#include <hip/hip_runtime.h>
#include <stdint.h>

#define NUM_GRAPHS 8192
#define NODES_PER_GRAPH 128
#define TOTAL_NODES (NUM_GRAPHS * NODES_PER_GRAPH)
#define C 128
#define GGROUPS (NUM_GRAPHS / 16)   // 512 graph-groups of 16
#define CSPLIT 4                    // each wave does 2 of the 8 col-tiles

typedef __attribute__((ext_vector_type(8))) short bf16x8;
typedef __attribute__((ext_vector_type(4))) float f32x4;

// f32 -> bf16 bits, round-to-nearest-even
static __device__ __forceinline__ short f2bf(float f) {
    union { float f; uint32_t u; } v; v.f = f;
    const uint32_t u = v.u;
    return (short)((u + 0x7fffu + ((u >> 16) & 1u)) >> 16);
}

// First occurrence of graph g in sorted `batch`. Fast path: uniform guess
// g*(TOTAL/NUM) verified with 2 cached loads (exact for this input).
// Fallback: lower_bound binary search (correct for any sorted batch).
// NOTE (R4 post-mortem): speculatively issuing the x-row loads at the guess
// in parallel with this check REGRESSED (13.3 -> 15.3 us) — plausibly the
// 32-VGPR float4 live range across the fallback branch; reverted to the
// best-measured R3 structure.
static __device__ __forceinline__ int first_index(const int* __restrict__ batch, int g) {
    const int p = g * (TOTAL_NODES / NUM_GRAPHS);
    if (batch[p] == g && (p == 0 || batch[p - 1] < g)) return p;
    int lo = 0, hi = TOTAL_NODES;
    while (lo < hi) {
        const int mid = (lo + hi) >> 1;
        if (batch[mid] < g) lo = mid + 1; else hi = mid;
    }
    return lo;
}

// Fused: one wave per (16 graphs x 32 cols). grid = CSPLIT*GGROUPS blocks of 64.
// bid%GGROUPS = graph-group -> all col-splits of a group share bid%8 (same XCD),
// so gathered x rows are fetched into that XCD's L2 once.
__global__ __launch_bounds__(64) void pool_linear_fused(
        const float* __restrict__ x, const int* __restrict__ batch,
        const float* __restrict__ W, const float* __restrict__ bias,
        float* __restrict__ out) {
    const int bid = blockIdx.x;
    const int gg  = bid & (GGROUPS - 1);   // graph-group
    const int cth = bid >> 9;              // 0..3 -> col-tiles 2*cth, 2*cth+1

    const int l  = threadIdx.x;
    const int r  = l & 15;   // A-row / B-col / D-col within tile
    const int kg = l >> 4;   // k-group
    const int gbase = gg * 16;

    // Per-lane first-node index (2 cached loads on the fast path).
    const int fi = first_index(batch, gbase + r);

    // A fragments: gathered row of x -> bf16. Loaded once, reused for both col-tiles.
    const float* xrow = x + (size_t)fi * C;
    bf16x8 a[4];
#pragma unroll
    for (int kc = 0; kc < 4; ++kc) {
        const int k0 = kc * 32 + kg * 8;
        const float4 lo = *reinterpret_cast<const float4*>(xrow + k0);
        const float4 hi = *reinterpret_cast<const float4*>(xrow + k0 + 4);
        a[kc][0] = f2bf(lo.x); a[kc][1] = f2bf(lo.y); a[kc][2] = f2bf(lo.z); a[kc][3] = f2bf(lo.w);
        a[kc][4] = f2bf(hi.x); a[kc][5] = f2bf(hi.y); a[kc][6] = f2bf(hi.z); a[kc][7] = f2bf(hi.w);
    }

#pragma unroll
    for (int t = 0; t < 2; ++t) {
        const int ct  = cth * 2 + t;
        const int col = ct * 16 + r;                 // B col = D col = lane&15
        const float* wrow = W + (size_t)col * C;     // out[g][col] = sum_k x[fi][k]*W[col][k]
        const float bc = bias[col];
        f32x4 acc = {bc, bc, bc, bc};
#pragma unroll
        for (int kc = 0; kc < 4; ++kc) {
            const int k0 = kc * 32 + kg * 8;
            const float4 lo = *reinterpret_cast<const float4*>(wrow + k0);
            const float4 hi = *reinterpret_cast<const float4*>(wrow + k0 + 4);
            bf16x8 bf;
            bf[0] = f2bf(lo.x); bf[1] = f2bf(lo.y); bf[2] = f2bf(lo.z); bf[3] = f2bf(lo.w);
            bf[4] = f2bf(hi.x); bf[5] = f2bf(hi.y); bf[6] = f2bf(hi.z); bf[7] = f2bf(hi.w);
            acc = __builtin_amdgcn_mfma_f32_16x16x32_bf16(a[kc], bf, acc, 0, 0, 0);
        }
        // C/D layout: col = lane&15, row = (lane>>4)*4 + reg
#pragma unroll
        for (int reg = 0; reg < 4; ++reg) {
            const int row = gbase + kg * 4 + reg;
            out[(size_t)row * C + col] = acc[reg];
        }
    }
}

extern "C" void kernel_launch(void* const* d_in, const int* in_sizes, int n_in,
                              void* d_out, int out_size, void* d_ws, size_t ws_size,
                              hipStream_t stream) {
    const float* x     = (const float*)d_in[0];
    const int*   batch = (const int*)d_in[1];
    const float* W     = (const float*)d_in[2];
    const float* b     = (const float*)d_in[3];
    float*       out   = (float*)d_out;

    pool_linear_fused<<<CSPLIT * GGROUPS, 64, 0, stream>>>(x, batch, W, b, out);
}